// Round 1
// baseline (201.792 us; speedup 1.0000x reference)
//
#include <hip/hip_runtime.h>

// RoIAlign (faithful port of the reference's quirky crop_and_resize):
// - boxes are [x1,y1,x2,y2]/stride but consumed as normalized [y1,x1,y2,x2],
//   then scaled by (H-1) again -> almost all sample points are out of range
//   -> valid mask false -> zero output. We reproduce exactly.
// - One thread per float4 of channels: 64 lanes cover one (n,i,j) cell's 256
//   channels -> fully coalesced 16B/lane stores.
// - fp contract off so mul/add ordering matches the reference (validity
//   boundary + bilinear weights).

constexpr int CH = 256;

__global__ __launch_bounds__(256)
void roi_align_kernel(const float* __restrict__ p2,
                      const float* __restrict__ p3,
                      const float* __restrict__ p4,
                      const float* __restrict__ p5,
                      const float* __restrict__ rois,
                      float* __restrict__ out,
                      int nrois)
{
#pragma clang fp contract(off)
    int idx = blockIdx.x * blockDim.x + threadIdx.x;
    int total = nrois * 49 * 64;
    if (idx >= total) return;

    int c4   = idx & 63;          // which float4 of the 256 channels
    int t    = idx >> 6;
    int n    = t / 49;            // roi index
    int cell = t - n * 49;
    int i    = cell / 7;          // output y
    int j    = cell - i * 7;      // output x

    const float* r = rois + n * 5;
    int   b  = (int)r[0];
    float x1 = r[1], y1 = r[2], x2 = r[3], y2 = r[4];

    // FPN level: clip(round(4 + log2(sqrt(h*w)/224)), 2, 5); rintf = round-half-even
    float rw = x2 - x1, rh = y2 - y1;
    float lvl = 4.0f + log2f(sqrtf(rh * rw) / 224.0f);
    int level = (int)rintf(lvl);
    level = level < 2 ? 2 : (level > 5 ? 5 : level);

    const float* fm; int H; float inv_s;
    if (level == 2)      { fm = p2; H = 256; inv_s = 0.25f;    }
    else if (level == 3) { fm = p3; H = 128; inv_s = 0.125f;   }
    else if (level == 4) { fm = p4; H = 64;  inv_s = 0.0625f;  }
    else                 { fm = p5; H = 32;  inv_s = 0.03125f; }

    // Quirk reproduced: boxes fed as [x1,y1,x2,y2]*inv_s, read as [y1,x1,y2,x2]
    float cy1 = x1 * inv_s, cx1 = y1 * inv_s;
    float cy2 = x2 * inv_s, cx2 = y2 * inv_s;
    float Hm1 = (float)(H - 1);
    float h_scale = (cy2 - cy1) * Hm1 / 6.0f;
    float w_scale = (cx2 - cx1) * Hm1 / 6.0f;
    float in_y = cy1 * Hm1 + (float)i * h_scale;
    float in_x = cx1 * Hm1 + (float)j * w_scale;

    float4* op = (float4*)(out + (size_t)(n * 49 + cell) * CH) + c4;

    bool valid = (in_y >= 0.0f) & (in_y <= Hm1) & (in_x >= 0.0f) & (in_x <= Hm1);
    if (!valid) {
        *op = make_float4(0.f, 0.f, 0.f, 0.f);
        return;
    }

    float fy = floorf(in_y), fx = floorf(in_x);
    int y0 = (int)fminf(fmaxf(fy, 0.f), Hm1);
    int yc = (int)fminf(fmaxf(ceilf(in_y), 0.f), Hm1);
    int x0 = (int)fminf(fmaxf(fx, 0.f), Hm1);
    int xc = (int)fminf(fmaxf(ceilf(in_x), 0.f), Hm1);
    float ly = in_y - fy, lx = in_x - fx;

    const float* img = fm + (size_t)b * H * H * CH;
    const float4 vtl = *((const float4*)(img + ((size_t)y0 * H + x0) * CH) + c4);
    const float4 vtr = *((const float4*)(img + ((size_t)y0 * H + xc) * CH) + c4);
    const float4 vbl = *((const float4*)(img + ((size_t)yc * H + x0) * CH) + c4);
    const float4 vbr = *((const float4*)(img + ((size_t)yc * H + xc) * CH) + c4);

    float4 res;
    float top, bot;
    top = vtl.x + (vtr.x - vtl.x) * lx;
    bot = vbl.x + (vbr.x - vbl.x) * lx;
    res.x = top + (bot - top) * ly;
    top = vtl.y + (vtr.y - vtl.y) * lx;
    bot = vbl.y + (vbr.y - vbl.y) * lx;
    res.y = top + (bot - top) * ly;
    top = vtl.z + (vtr.z - vtl.z) * lx;
    bot = vbl.z + (vbr.z - vbl.z) * lx;
    res.z = top + (bot - top) * ly;
    top = vtl.w + (vtr.w - vtl.w) * lx;
    bot = vbl.w + (vbr.w - vbl.w) * lx;
    res.w = top + (bot - top) * ly;

    *op = res;
}

extern "C" void kernel_launch(void* const* d_in, const int* in_sizes, int n_in,
                              void* d_out, int out_size, void* d_ws, size_t ws_size,
                              hipStream_t stream)
{
    const float* p2   = (const float*)d_in[0];
    const float* p3   = (const float*)d_in[1];
    const float* p4   = (const float*)d_in[2];
    const float* p5   = (const float*)d_in[3];
    const float* rois = (const float*)d_in[4];
    float* out = (float*)d_out;

    int nrois = in_sizes[4] / 5;
    int total = nrois * 49 * 64;       // one thread per float4 of channels
    int block = 256;
    int grid  = (total + block - 1) / block;
    roi_align_kernel<<<grid, block, 0, stream>>>(p2, p3, p4, p5, rois, out, nrois);
}

// Round 2
// 197.525 us; speedup vs baseline: 1.0216x; 1.0216x over previous
//
#include <hip/hip_runtime.h>

// RoIAlign, two-phase:
//   K1: per-ROI params (level, scales, bases) -> d_ws (1000 x 32B)
//   K2: one thread per float4 of channels; 64 lanes = one (n,i,j) cell;
//       params are wave-uniform loads; nontemporal dwordx4 stores.
// Quirk reproduced from the reference: boxes fed as [x1,y1,x2,y2]/stride but
// consumed as normalized [y1,x1,y2,x2] and rescaled by (H-1) -> nearly all
// sample points invalid -> zero output. fp contract off everywhere so the
// mul/add rounding matches the unfused jax reference exactly.

constexpr int CH = 256;

typedef float v4f __attribute__((ext_vector_type(4)));

__global__ __launch_bounds__(256)
void roi_params_kernel(const float* __restrict__ rois,
                       v4f* __restrict__ params, int nrois)
{
#pragma clang fp contract(off)
    int n = blockIdx.x * blockDim.x + threadIdx.x;
    if (n >= nrois) return;
    const float* r = rois + n * 5;
    int   b  = (int)r[0];
    float x1 = r[1], y1 = r[2], x2 = r[3], y2 = r[4];

    // level = clip(round(4 + log2(sqrt(h*w)/224)), 2, 5); rintf = RNE like jnp.round
    float lvl = 4.0f + log2f(sqrtf((y2 - y1) * (x2 - x1)) / 224.0f);
    int level = (int)rintf(lvl);
    level = level < 2 ? 2 : (level > 5 ? 5 : level);

    int H; float inv_s;
    if (level == 2)      { H = 256; inv_s = 0.25f;    }
    else if (level == 3) { H = 128; inv_s = 0.125f;   }
    else if (level == 4) { H = 64;  inv_s = 0.0625f;  }
    else                 { H = 32;  inv_s = 0.03125f; }

    // Quirk: [x1,y1,x2,y2]*inv_s read as [y1,x1,y2,x2]
    float cy1 = x1 * inv_s, cx1 = y1 * inv_s;
    float cy2 = x2 * inv_s, cx2 = y2 * inv_s;
    float Hm1 = (float)(H - 1);
    float h_scale = (cy2 - cy1) * Hm1 / 6.0f;
    float w_scale = (cx2 - cx1) * Hm1 / 6.0f;

    v4f pa; pa.x = cy1 * Hm1; pa.y = h_scale; pa.z = cx1 * Hm1; pa.w = w_scale;
    v4f pb; pb.x = Hm1;
    pb.y = __int_as_float(H);
    pb.z = __int_as_float(b * H * H * CH);   // element offset of image b
    pb.w = __int_as_float(level);
    params[n * 2 + 0] = pa;
    params[n * 2 + 1] = pb;
}

__global__ __launch_bounds__(256)
void roi_align_main(const float* __restrict__ p2, const float* __restrict__ p3,
                    const float* __restrict__ p4, const float* __restrict__ p5,
                    const v4f* __restrict__ params,
                    float* __restrict__ out, int nrois)
{
#pragma clang fp contract(off)
    int idx = blockIdx.x * blockDim.x + threadIdx.x;
    int total = nrois * 49 * 64;
    if (idx >= total) return;

    int c4   = idx & 63;
    int t    = idx >> 6;
    int n    = t / 49;
    int cell = t - n * 49;
    int i    = cell / 7;
    int j    = cell - i * 7;

    v4f pa = params[n * 2 + 0];
    v4f pb = params[n * 2 + 1];

    float in_y = pa.x + (float)i * pa.y;   // contract off: mul, then add
    float in_x = pa.z + (float)j * pa.w;
    float Hm1  = pb.x;

    v4f* op = (v4f*)out + idx;   // idx == (t*64 + c4), dense float4 index

    bool valid = (in_y >= 0.0f) & (in_y <= Hm1) & (in_x >= 0.0f) & (in_x <= Hm1);
    if (!valid) {
        v4f z; z.x = 0.f; z.y = 0.f; z.z = 0.f; z.w = 0.f;
        __builtin_nontemporal_store(z, op);
        return;
    }

    int H       = __float_as_int(pb.y);
    int img_off = __float_as_int(pb.z);
    int level   = __float_as_int(pb.w);
    const float* fm = level == 2 ? p2 : level == 3 ? p3 : level == 4 ? p4 : p5;

    float fy = floorf(in_y), fx = floorf(in_x);
    // valid => floor/ceil already land in [0, H-1]; clamps kept (2 instrs, safety)
    int y0 = (int)fminf(fmaxf(fy, 0.f), Hm1);
    int yc = (int)fminf(fmaxf(ceilf(in_y), 0.f), Hm1);
    int x0 = (int)fminf(fmaxf(fx, 0.f), Hm1);
    int xc = (int)fminf(fmaxf(ceilf(in_x), 0.f), Hm1);
    float ly = in_y - fy, lx = in_x - fx;

    const float* img = fm + img_off;
    const v4f vtl = *((const v4f*)(img + ((size_t)y0 * H + x0) * CH) + c4);
    const v4f vtr = *((const v4f*)(img + ((size_t)y0 * H + xc) * CH) + c4);
    const v4f vbl = *((const v4f*)(img + ((size_t)yc * H + x0) * CH) + c4);
    const v4f vbr = *((const v4f*)(img + ((size_t)yc * H + xc) * CH) + c4);

    v4f res;
    {
        v4f top, bot;
        top = vtl + (vtr - vtl) * lx;
        bot = vbl + (vbr - vbl) * lx;
        res = top + (bot - top) * ly;
    }
    __builtin_nontemporal_store(res, op);
}

extern "C" void kernel_launch(void* const* d_in, const int* in_sizes, int n_in,
                              void* d_out, int out_size, void* d_ws, size_t ws_size,
                              hipStream_t stream)
{
    const float* p2   = (const float*)d_in[0];
    const float* p3   = (const float*)d_in[1];
    const float* p4   = (const float*)d_in[2];
    const float* p5   = (const float*)d_in[3];
    const float* rois = (const float*)d_in[4];
    float* out = (float*)d_out;
    v4f* params = (v4f*)d_ws;

    int nrois = in_sizes[4] / 5;

    roi_params_kernel<<<(nrois + 255) / 256, 256, 0, stream>>>(rois, params, nrois);

    int total = nrois * 49 * 64;
    roi_align_main<<<(total + 255) / 256, 256, 0, stream>>>(p2, p3, p4, p5,
                                                            params, out, nrois);
}